// Round 10
// baseline (75.701 us; speedup 1.0000x reference)
//
#include <hip/hip_runtime.h>

// ChamferDistance  B=16, N=M=4096, D=3, fp32 in/out (scalar out).
// Two MFMA passes (dir0: rows of dist(p1,p2); dir1: rows of dist(p2,p1)).
// d(a,b) = sum_k A[k]*B[k], 13 bf16 hi/lo slots in K=32 (k-groups 0,1 real;
// k-groups 2,3 zero in A so B's lanes 32-63 may hold any finite data).
#define BQ     16
#define NPTS   4096
#define TOTAL  (BQ * NPTS)              // 65536 points per side
#define NPART  128
#define SIDE_TILES    (TOTAL / 16)      // 4096 col-tiles per side
#define PANEL_U4_SIDE ((size_t)SIDE_TILES * 32)   // 131072 uint4 per side (2 MiB)
#define WS_MIN_BYTES  ((size_t)2 * TOTAL * 4)     // 512 KiB
#define WS_NEED (WS_MIN_BYTES + 2 * PANEL_U4_SIDE * 16 + (size_t)NPART * 4)

typedef __attribute__((ext_vector_type(8))) short short8;
typedef __attribute__((ext_vector_type(4))) float f32x4;

__device__ __forceinline__ unsigned short f2bf(float x) {
    union { float f; unsigned u; } v; v.f = x;
    unsigned r = v.u + 0x7FFFu + ((v.u >> 16) & 1u);    // RNE
    return (unsigned short)(r >> 16);
}
__device__ __forceinline__ float bf2f(unsigned short h) {
    union { float f; unsigned u; } v; v.u = ((unsigned)h) << 16; return v.f;
}
#define BF_ONE 0x3F80

// B-role, k-position (g, j), g = lane32>>4:
//  g0: m2xh m2yh m2zh m2xl m2yl m2zl m2xh m2yh
//  g1: m2zh  1    1   b2H  b2L   0    0    0
__device__ __forceinline__ uint4 make_bslots16(const float* __restrict__ pts,
                                               int tile, int lane32) {
    const int g = lane32 >> 4;
    const float* pp = pts + (size_t)(tile * 16 + (lane32 & 15)) * 3;
    const float x = pp[0], y = pp[1], z = pp[2];
    const unsigned short xh = f2bf(x), yh = f2bf(y), zh = f2bf(z);
    const unsigned short xl = f2bf(x - bf2f(xh)), yl = f2bf(y - bf2f(yh)),
                         zl = f2bf(z - bf2f(zh));
    const unsigned short m2xh = f2bf(-2.0f * bf2f(xh)), m2yh = f2bf(-2.0f * bf2f(yh)),
                         m2zh = f2bf(-2.0f * bf2f(zh));
    const unsigned short m2xl = f2bf(-2.0f * bf2f(xl)), m2yl = f2bf(-2.0f * bf2f(yl)),
                         m2zl = f2bf(-2.0f * bf2f(zl));
    const float s2 = fmaf(x, x, fmaf(y, y, z * z));
    const unsigned short s2h = f2bf(s2);
    const unsigned short s2l = f2bf(s2 - bf2f(s2h));
    unsigned short s[8];
    if (g == 0) { s[0]=m2xh; s[1]=m2yh; s[2]=m2zh; s[3]=m2xl;   s[4]=m2yl;   s[5]=m2zl; s[6]=m2xh; s[7]=m2yh; }
    else        { s[0]=m2zh; s[1]=BF_ONE; s[2]=BF_ONE; s[3]=s2h; s[4]=s2l;   s[5]=0;    s[6]=0;    s[7]=0;    }
    uint4 o;
    o.x = (unsigned)s[0] | ((unsigned)s[1] << 16);
    o.y = (unsigned)s[2] | ((unsigned)s[3] << 16);
    o.z = (unsigned)s[4] | ((unsigned)s[5] << 16);
    o.w = (unsigned)s[6] | ((unsigned)s[7] << 16);
    return o;
}

// A-role paired with B above:
//  g0: xh yh zh xh yh zh xl yl
//  g1: zl s2h s2l 1 1 0 0 0
__device__ __forceinline__ short8 make_aslots16(const float* __restrict__ pts,
                                                int point, int g) {
    const float* pp = pts + (size_t)point * 3;
    const float x = pp[0], y = pp[1], z = pp[2];
    const unsigned short xh = f2bf(x), yh = f2bf(y), zh = f2bf(z);
    const unsigned short xl = f2bf(x - bf2f(xh)), yl = f2bf(y - bf2f(yh)),
                         zl = f2bf(z - bf2f(zh));
    const float s2 = fmaf(x, x, fmaf(y, y, z * z));
    const unsigned short s2h = f2bf(s2);
    const unsigned short s2l = f2bf(s2 - bf2f(s2h));
    unsigned short s[8];
    if (g == 0) { s[0]=xh; s[1]=yh; s[2]=zh; s[3]=xh;     s[4]=yh;     s[5]=zh; s[6]=xl; s[7]=yl; }
    else        { s[0]=zl; s[1]=s2h; s[2]=s2l; s[3]=BF_ONE; s[4]=BF_ONE; s[5]=0; s[6]=0; s[7]=0; }
    union { unsigned u[4]; short8 v; } o;
    o.u[0] = (unsigned)s[0] | ((unsigned)s[1] << 16);
    o.u[1] = (unsigned)s[2] | ((unsigned)s[3] << 16);
    o.u[2] = (unsigned)s[4] | ((unsigned)s[5] << 16);
    o.u[3] = (unsigned)s[6] | ((unsigned)s[7] << 16);
    return o.v;
}

// Build both panels (side0 = p1, side1 = p2) + init wsmin.
__global__ __launch_bounds__(256) void cd_prep(const float* __restrict__ p1,
                                               const float* __restrict__ p2,
                                               unsigned* __restrict__ wsmin,
                                               uint4* __restrict__ panels) {
    const int tid = blockIdx.x * 256 + threadIdx.x;   // [0, 262144)
    if (tid < 2 * TOTAL) wsmin[tid] = 0x7F800000u;    // +inf
    const int side = tid >> 17;                       // 131072 slots per side
    const int l    = tid & 131071;
    const float* pts = side ? p2 : p1;
    panels[tid] = make_bslots16(pts, l >> 5, l & 31);
}

// Main: wave = 128 rows (8 x 16-row subtiles), block = 4 waves = 512 rows.
// Each wave sweeps 64 col-tiles (colgroup).  grid = (16b*8rg*4cg, 2 dirs).
// Depth-2 pair pipeline (R9 fix: cover ~200cyc L2 latency with ~2 computes).
__global__ __launch_bounds__(256, 4) void cd_pass(
        const float* __restrict__ p1, const float* __restrict__ p2,
        const uint4* __restrict__ panels, unsigned* __restrict__ wsmin) {
    const int dir  = blockIdx.y;
    const float* __restrict__ A = dir ? p2 : p1;
    const uint4* __restrict__ panel = panels + (dir ? 0 : PANEL_U4_SIDE);
    unsigned* __restrict__ outmin = wsmin + dir * TOTAL;

    const int bx   = blockIdx.x;
    const int b    = bx >> 5;                         // batch
    const int rg   = (bx >> 2) & 7;                   // rowgroup (512 rows)
    const int cg   = bx & 3;                          // colgroup (64 col-tiles)
    const int wave = threadIdx.x >> 6;
    const int lane = threadIdx.x & 63;
    const int half = lane >> 5;                       // 0: real k-groups, 1: zero-A

    const int rowbase = b * NPTS + rg * 512 + wave * 128;

    // A fragments: 8 subtiles of 16 rows; lanes >=32 carry zero k-groups,
    // which zero out whatever finite data B holds in those lanes.
    short8 az; { union { unsigned u[4]; short8 v; } z = {{0,0,0,0}}; az = z.v; }
    short8 a0=az,a1=az,a2=az,a3=az,a4=az,a5=az,a6=az,a7=az;
    if (half == 0) {
        const int g = (lane >> 4) & 1, r = lane & 15;
        a0 = make_aslots16(A, rowbase +   0 + r, g);
        a1 = make_aslots16(A, rowbase +  16 + r, g);
        a2 = make_aslots16(A, rowbase +  32 + r, g);
        a3 = make_aslots16(A, rowbase +  48 + r, g);
        a4 = make_aslots16(A, rowbase +  64 + r, g);
        a5 = make_aslots16(A, rowbase +  80 + r, g);
        a6 = make_aslots16(A, rowbase +  96 + r, g);
        a7 = make_aslots16(A, rowbase + 112 + r, g);
    }

    f32x4 zero = {0.0f, 0.0f, 0.0f, 0.0f};
    f32x4 r0,r1,r2,r3,r4,r5,r6,r7;
#pragma unroll
    for (int e = 0; e < 4; ++e) {
        r0[e]=3.0e38f; r1[e]=3.0e38f; r2[e]=3.0e38f; r3[e]=3.0e38f;
        r4[e]=3.0e38f; r5[e]=3.0e38f; r6[e]=3.0e38f; r7[e]=3.0e38f;
    }

    // All 64 lanes load the same 32 fragment slots (lane&31): halves distinct
    // bytes; lanes 32-63 get duplicate finite data (zeroed by A).
    const uint4* __restrict__ bp =
        panel + (size_t)(b * 256 + cg * 64) * 32 + (lane & 31);

#define CD_COMPUTE(C0, C1)                                                   \
    do {                                                                     \
        const short8 bf0 = *reinterpret_cast<const short8*>(&(C0));          \
        const short8 bf1 = *reinterpret_cast<const short8*>(&(C1));          \
        f32x4 d0, d1;                                                        \
        d0 = __builtin_amdgcn_mfma_f32_16x16x32_bf16(a0, bf0, zero, 0,0,0);  \
        d1 = __builtin_amdgcn_mfma_f32_16x16x32_bf16(a0, bf1, zero, 0,0,0);  \
        _Pragma("unroll") for (int e = 0; e < 4; ++e)                        \
            r0[e] = fminf(r0[e], fminf(d0[e], d1[e]));                       \
        d0 = __builtin_amdgcn_mfma_f32_16x16x32_bf16(a1, bf0, zero, 0,0,0);  \
        d1 = __builtin_amdgcn_mfma_f32_16x16x32_bf16(a1, bf1, zero, 0,0,0);  \
        _Pragma("unroll") for (int e = 0; e < 4; ++e)                        \
            r1[e] = fminf(r1[e], fminf(d0[e], d1[e]));                       \
        d0 = __builtin_amdgcn_mfma_f32_16x16x32_bf16(a2, bf0, zero, 0,0,0);  \
        d1 = __builtin_amdgcn_mfma_f32_16x16x32_bf16(a2, bf1, zero, 0,0,0);  \
        _Pragma("unroll") for (int e = 0; e < 4; ++e)                        \
            r2[e] = fminf(r2[e], fminf(d0[e], d1[e]));                       \
        d0 = __builtin_amdgcn_mfma_f32_16x16x32_bf16(a3, bf0, zero, 0,0,0);  \
        d1 = __builtin_amdgcn_mfma_f32_16x16x32_bf16(a3, bf1, zero, 0,0,0);  \
        _Pragma("unroll") for (int e = 0; e < 4; ++e)                        \
            r3[e] = fminf(r3[e], fminf(d0[e], d1[e]));                       \
        d0 = __builtin_amdgcn_mfma_f32_16x16x32_bf16(a4, bf0, zero, 0,0,0);  \
        d1 = __builtin_amdgcn_mfma_f32_16x16x32_bf16(a4, bf1, zero, 0,0,0);  \
        _Pragma("unroll") for (int e = 0; e < 4; ++e)                        \
            r4[e] = fminf(r4[e], fminf(d0[e], d1[e]));                       \
        d0 = __builtin_amdgcn_mfma_f32_16x16x32_bf16(a5, bf0, zero, 0,0,0);  \
        d1 = __builtin_amdgcn_mfma_f32_16x16x32_bf16(a5, bf1, zero, 0,0,0);  \
        _Pragma("unroll") for (int e = 0; e < 4; ++e)                        \
            r5[e] = fminf(r5[e], fminf(d0[e], d1[e]));                       \
        d0 = __builtin_amdgcn_mfma_f32_16x16x32_bf16(a6, bf0, zero, 0,0,0);  \
        d1 = __builtin_amdgcn_mfma_f32_16x16x32_bf16(a6, bf1, zero, 0,0,0);  \
        _Pragma("unroll") for (int e = 0; e < 4; ++e)                        \
            r6[e] = fminf(r6[e], fminf(d0[e], d1[e]));                       \
        d0 = __builtin_amdgcn_mfma_f32_16x16x32_bf16(a7, bf0, zero, 0,0,0);  \
        d1 = __builtin_amdgcn_mfma_f32_16x16x32_bf16(a7, bf1, zero, 0,0,0);  \
        _Pragma("unroll") for (int e = 0; e < 4; ++e)                        \
            r7[e] = fminf(r7[e], fminf(d0[e], d1[e]));                       \
    } while (0)

    // 64 tiles = 32 pairs.  Depth-2 pair pipeline, unroll-2 (static names):
    // loads for pair j+2/j+3 issue ~2 computes (~400 cyc) before use.
    uint4 c0 = bp[0 * 32], c1 = bp[1 * 32];
    uint4 c2 = bp[2 * 32], c3 = bp[3 * 32];
#pragma unroll 1
    for (int j = 0; j < 30; j += 2) {
        uint4 n0 = bp[(2 * j + 4) * 32], n1 = bp[(2 * j + 5) * 32];
        CD_COMPUTE(c0, c1);
        uint4 n2 = bp[(2 * j + 6) * 32], n3 = bp[(2 * j + 7) * 32];
        CD_COMPUTE(c2, c3);
        c0 = n0; c1 = n1; c2 = n2; c3 = n3;
    }
    CD_COMPUTE(c0, c1);
    CD_COMPUTE(c2, c3);
#undef CD_COMPUTE

    // Row epilogue: butterfly over the 16 cols (within each 16-lane group),
    // then atomicMin per row.  Row = s*16 + (lane>>4)*4 + e  (m89/m91 layout).
    const int rgrp = lane >> 4;
#pragma unroll
    for (int s = 0; s < 8; ++s) {
        f32x4 rv = (s==0)?r0:(s==1)?r1:(s==2)?r2:(s==3)?r3:(s==4)?r4:(s==5)?r5:(s==6)?r6:r7;
#pragma unroll
        for (int e = 0; e < 4; ++e) {
            float v = rv[e];
            v = fminf(v, __shfl_xor(v, 1));
            v = fminf(v, __shfl_xor(v, 2));
            v = fminf(v, __shfl_xor(v, 4));
            v = fminf(v, __shfl_xor(v, 8));
            if ((lane & 15) == 0)
                atomicMin(&outmin[rowbase + s * 16 + rgrp * 4 + e],
                          __float_as_uint(fmaxf(v, 0.0f)));
        }
    }
}

// ---------------- deterministic two-stage sum ----------------
__global__ __launch_bounds__(256) void cd_reduce1(const float* __restrict__ wsmin,
                                                  float* __restrict__ partial) {
    __shared__ float sred[256];
    const float4* __restrict__ v = (const float4*)wsmin;
    const int i = blockIdx.x * 256 + threadIdx.x;     // 128*256 == 2*TOTAL/4
    float4 x = v[i];
    sred[threadIdx.x] = (x.x + x.y) + (x.z + x.w);
    __syncthreads();
    for (int st = 128; st > 0; st >>= 1) {
        if (threadIdx.x < st) sred[threadIdx.x] += sred[threadIdx.x + st];
        __syncthreads();
    }
    if (threadIdx.x == 0) partial[blockIdx.x] = sred[0];
}

__global__ __launch_bounds__(NPART) void cd_reduce2(const float* __restrict__ partial,
                                                    float* __restrict__ out) {
    __shared__ float sred[NPART];
    sred[threadIdx.x] = partial[threadIdx.x];
    __syncthreads();
    for (int st = NPART / 2; st > 0; st >>= 1) {
        if (threadIdx.x < st) sred[threadIdx.x] += sred[threadIdx.x + st];
        __syncthreads();
    }
    if (threadIdx.x == 0) out[0] = sred[0] * (1.0f / (float)BQ);
}

// ---------------- fallback (ws too small): R2 LDS-scalar path ----------------
__global__ __launch_bounds__(256) void cd_init_ws(unsigned int* __restrict__ ws) {
    ws[blockIdx.x * 256 + threadIdx.x] = 0x7F800000u;
}
#define F_APT 8
__global__ __launch_bounds__(256) void cd_min_lds(
        const float* __restrict__ p1, const float* __restrict__ p2,
        unsigned int* __restrict__ wsmin) {
    const int dir = blockIdx.y;
    const float* __restrict__ Aset = dir ? p2 : p1;
    const float* __restrict__ Bset = dir ? p1 : p2;
    unsigned int* __restrict__ outmin = wsmin + dir * TOTAL;
    const int atile = blockIdx.x / 16;
    const int mtile = blockIdx.x % 16;
    const int a0 = atile * 2048;
    const int m0 = (a0 / NPTS) * NPTS + mtile * 256;
    __shared__ float4 sbf[256];
    {
        const float* bpn = Bset + (size_t)(m0 + threadIdx.x) * 3;
        float bx = bpn[0], by = bpn[1], bz = bpn[2];
        sbf[threadIdx.x] = make_float4(-2.0f*bx, -2.0f*by, -2.0f*bz,
                                       fmaf(bx,bx,fmaf(by,by,bz*bz)));
    }
    __syncthreads();
    float ax[F_APT], ay[F_APT], az_[F_APT], q2[F_APT], mn[F_APT];
#pragma unroll
    for (int k = 0; k < F_APT; ++k) {
        const int ai = a0 + k*256 + threadIdx.x;
        const float* ap = Aset + (size_t)ai * 3;
        ax[k]=ap[0]; ay[k]=ap[1]; az_[k]=ap[2];
        q2[k]=fmaf(ax[k],ax[k],fmaf(ay[k],ay[k],az_[k]*az_[k]));
        mn[k]=3.0e38f;
    }
#pragma unroll 2
    for (int j = 0; j < 256; j += 2) {
        const float4 b0 = sbf[j], b1 = sbf[j+1];
#pragma unroll
        for (int k = 0; k < F_APT; ++k) {
            float d0 = fmaf(az_[k],b0.z,b0.w); d0=fmaf(ay[k],b0.y,d0); d0=fmaf(ax[k],b0.x,d0);
            float d1 = fmaf(az_[k],b1.z,b1.w); d1=fmaf(ay[k],b1.y,d1); d1=fmaf(ax[k],b1.x,d1);
            mn[k] = fminf(fminf(mn[k], d0), d1);
        }
    }
#pragma unroll
    for (int k = 0; k < F_APT; ++k) {
        const int ai = a0 + k*256 + threadIdx.x;
        atomicMin(&outmin[ai], __float_as_uint(fmaxf(q2[k]+mn[k], 0.0f)));
    }
}
__global__ __launch_bounds__(1024) void cd_reduce_single(const float* __restrict__ wsmin,
                                                         float* __restrict__ out) {
    __shared__ float sred[1024];
    const float4* __restrict__ v = (const float4*)wsmin;
    float s = 0.0f;
    for (int i = threadIdx.x; i < (2*TOTAL)/4; i += 1024) {
        float4 x = v[i]; s += (x.x + x.y) + (x.z + x.w);
    }
    sred[threadIdx.x] = s;
    __syncthreads();
    for (int st = 512; st > 0; st >>= 1) {
        if (threadIdx.x < st) sred[threadIdx.x] += sred[threadIdx.x + st];
        __syncthreads();
    }
    if (threadIdx.x == 0) out[0] = sred[0] * (1.0f / (float)BQ);
}

extern "C" void kernel_launch(void* const* d_in, const int* in_sizes, int n_in,
                              void* d_out, int out_size, void* d_ws, size_t ws_size,
                              hipStream_t stream) {
    const float* p1 = (const float*)d_in[0];
    const float* p2 = (const float*)d_in[1];
    float* out = (float*)d_out;

    if (ws_size >= WS_NEED) {
        unsigned* wsmin = (unsigned*)d_ws;
        uint4* panels  = (uint4*)((char*)d_ws + WS_MIN_BYTES);
        float* partial = (float*)((char*)d_ws + WS_MIN_BYTES + 2 * PANEL_U4_SIDE * 16);

        cd_prep<<<1024, 256, 0, stream>>>(p1, p2, wsmin, panels);
        dim3 grid(512, 2, 1);
        cd_pass<<<grid, 256, 0, stream>>>(p1, p2, panels, wsmin);
        cd_reduce1<<<128, 256, 0, stream>>>((const float*)wsmin, partial);
        cd_reduce2<<<1, NPART, 0, stream>>>(partial, out);
    } else {
        unsigned* wsmin = (unsigned*)d_ws;                   // 512 KiB
        cd_init_ws<<<(2 * TOTAL) / 256, 256, 0, stream>>>(wsmin);
        dim3 grid(512, 2, 1);
        cd_min_lds<<<grid, 256, 0, stream>>>(p1, p2, wsmin);
        cd_reduce_single<<<1, 1024, 0, stream>>>((const float*)wsmin, out);
    }
}

// Round 11
// 43.386 us; speedup vs baseline: 1.7448x; 1.7448x over previous
//
#include <hip/hip_runtime.h>

// ChamferDistance  B=16, N=M=4096, D=3, fp32 in/out (scalar out).
// Two MFMA passes (dir0: rows of dist(p1,p2); dir1: rows of dist(p2,p1)).
// d(a,b) = sum_k A[k]*B[k], 13 bf16 hi/lo slots in K=32 (k-groups 0,1 real;
// k-groups 2,3 zero in A so B's lanes 32-63 may hold any finite data).
#define BQ     16
#define NPTS   4096
#define TOTAL  (BQ * NPTS)              // 65536 points per side
#define NPART  128
#define SIDE_TILES    (TOTAL / 16)      // 4096 col-tiles per side
#define PANEL_U4_SIDE ((size_t)SIDE_TILES * 32)   // 131072 uint4 per side (2 MiB)
#define WS_MIN_BYTES  ((size_t)2 * TOTAL * 4)     // 512 KiB
#define WS_NEED (WS_MIN_BYTES + 2 * PANEL_U4_SIDE * 16 + (size_t)NPART * 4)

typedef __attribute__((ext_vector_type(8))) short short8;
typedef __attribute__((ext_vector_type(4))) float f32x4;

__device__ __forceinline__ unsigned short f2bf(float x) {
    union { float f; unsigned u; } v; v.f = x;
    unsigned r = v.u + 0x7FFFu + ((v.u >> 16) & 1u);    // RNE
    return (unsigned short)(r >> 16);
}
__device__ __forceinline__ float bf2f(unsigned short h) {
    union { float f; unsigned u; } v; v.u = ((unsigned)h) << 16; return v.f;
}
#define BF_ONE 0x3F80

// B-role, k-position (g, j), g = lane32>>4:
//  g0: m2xh m2yh m2zh m2xl m2yl m2zl m2xh m2yh
//  g1: m2zh  1    1   b2H  b2L   0    0    0
__device__ __forceinline__ uint4 make_bslots16(const float* __restrict__ pts,
                                               int tile, int lane32) {
    const int g = lane32 >> 4;
    const float* pp = pts + (size_t)(tile * 16 + (lane32 & 15)) * 3;
    const float x = pp[0], y = pp[1], z = pp[2];
    const unsigned short xh = f2bf(x), yh = f2bf(y), zh = f2bf(z);
    const unsigned short xl = f2bf(x - bf2f(xh)), yl = f2bf(y - bf2f(yh)),
                         zl = f2bf(z - bf2f(zh));
    const unsigned short m2xh = f2bf(-2.0f * bf2f(xh)), m2yh = f2bf(-2.0f * bf2f(yh)),
                         m2zh = f2bf(-2.0f * bf2f(zh));
    const unsigned short m2xl = f2bf(-2.0f * bf2f(xl)), m2yl = f2bf(-2.0f * bf2f(yl)),
                         m2zl = f2bf(-2.0f * bf2f(zl));
    const float s2 = fmaf(x, x, fmaf(y, y, z * z));
    const unsigned short s2h = f2bf(s2);
    const unsigned short s2l = f2bf(s2 - bf2f(s2h));
    unsigned short s[8];
    if (g == 0) { s[0]=m2xh; s[1]=m2yh; s[2]=m2zh; s[3]=m2xl;   s[4]=m2yl;   s[5]=m2zl; s[6]=m2xh; s[7]=m2yh; }
    else        { s[0]=m2zh; s[1]=BF_ONE; s[2]=BF_ONE; s[3]=s2h; s[4]=s2l;   s[5]=0;    s[6]=0;    s[7]=0;    }
    uint4 o;
    o.x = (unsigned)s[0] | ((unsigned)s[1] << 16);
    o.y = (unsigned)s[2] | ((unsigned)s[3] << 16);
    o.z = (unsigned)s[4] | ((unsigned)s[5] << 16);
    o.w = (unsigned)s[6] | ((unsigned)s[7] << 16);
    return o;
}

// A-role paired with B above:
//  g0: xh yh zh xh yh zh xl yl
//  g1: zl s2h s2l 1 1 0 0 0
__device__ __forceinline__ short8 make_aslots16(const float* __restrict__ pts,
                                                int point, int g) {
    const float* pp = pts + (size_t)point * 3;
    const float x = pp[0], y = pp[1], z = pp[2];
    const unsigned short xh = f2bf(x), yh = f2bf(y), zh = f2bf(z);
    const unsigned short xl = f2bf(x - bf2f(xh)), yl = f2bf(y - bf2f(yh)),
                         zl = f2bf(z - bf2f(zh));
    const float s2 = fmaf(x, x, fmaf(y, y, z * z));
    const unsigned short s2h = f2bf(s2);
    const unsigned short s2l = f2bf(s2 - bf2f(s2h));
    unsigned short s[8];
    if (g == 0) { s[0]=xh; s[1]=yh; s[2]=zh; s[3]=xh;     s[4]=yh;     s[5]=zh; s[6]=xl; s[7]=yl; }
    else        { s[0]=zl; s[1]=s2h; s[2]=s2l; s[3]=BF_ONE; s[4]=BF_ONE; s[5]=0; s[6]=0; s[7]=0; }
    union { unsigned u[4]; short8 v; } o;
    o.u[0] = (unsigned)s[0] | ((unsigned)s[1] << 16);
    o.u[1] = (unsigned)s[2] | ((unsigned)s[3] << 16);
    o.u[2] = (unsigned)s[4] | ((unsigned)s[5] << 16);
    o.u[3] = (unsigned)s[6] | ((unsigned)s[7] << 16);
    return o.v;
}

// Build both panels (side0 = p1, side1 = p2) + init wsmin.
__global__ __launch_bounds__(256) void cd_prep(const float* __restrict__ p1,
                                               const float* __restrict__ p2,
                                               unsigned* __restrict__ wsmin,
                                               uint4* __restrict__ panels) {
    const int tid = blockIdx.x * 256 + threadIdx.x;   // [0, 262144)
    if (tid < 2 * TOTAL) wsmin[tid] = 0x7F800000u;    // +inf
    const int side = tid >> 17;                       // 131072 slots per side
    const int l    = tid & 131071;
    const float* pts = side ? p2 : p1;
    panels[tid] = make_bslots16(pts, l >> 5, l & 31);
}

// Main: wave = 128 rows (8 x 16-row subtiles), block = 4 waves = 512 rows.
// Each wave sweeps 64 col-tiles (colgroup).  grid = (16b*8rg*4cg, 2 dirs).
// Depth-1 pair pipeline (R10 lesson: depth-2 spilled to scratch, 65 MB of
// scratch writes; depth-1 keeps in-flight state at 16 VGPR, no spill).
__global__ __launch_bounds__(256, 4) void cd_pass(
        const float* __restrict__ p1, const float* __restrict__ p2,
        const uint4* __restrict__ panels, unsigned* __restrict__ wsmin) {
    const int dir  = blockIdx.y;
    const float* __restrict__ A = dir ? p2 : p1;
    const uint4* __restrict__ panel = panels + (dir ? 0 : PANEL_U4_SIDE);
    unsigned* __restrict__ outmin = wsmin + dir * TOTAL;

    const int bx   = blockIdx.x;
    const int b    = bx >> 5;                         // batch
    const int rg   = (bx >> 2) & 7;                   // rowgroup (512 rows)
    const int cg   = bx & 3;                          // colgroup (64 col-tiles)
    const int wave = threadIdx.x >> 6;
    const int lane = threadIdx.x & 63;
    const int half = lane >> 5;                       // 0: real k-groups, 1: zero-A

    const int rowbase = b * NPTS + rg * 512 + wave * 128;

    // A fragments: 8 subtiles of 16 rows; lanes >=32 carry zero k-groups,
    // which zero out whatever finite data B holds in those lanes.
    short8 az; { union { unsigned u[4]; short8 v; } z = {{0,0,0,0}}; az = z.v; }
    short8 a0=az,a1=az,a2=az,a3=az,a4=az,a5=az,a6=az,a7=az;
    if (half == 0) {
        const int g = (lane >> 4) & 1, r = lane & 15;
        a0 = make_aslots16(A, rowbase +   0 + r, g);
        a1 = make_aslots16(A, rowbase +  16 + r, g);
        a2 = make_aslots16(A, rowbase +  32 + r, g);
        a3 = make_aslots16(A, rowbase +  48 + r, g);
        a4 = make_aslots16(A, rowbase +  64 + r, g);
        a5 = make_aslots16(A, rowbase +  80 + r, g);
        a6 = make_aslots16(A, rowbase +  96 + r, g);
        a7 = make_aslots16(A, rowbase + 112 + r, g);
    }

    f32x4 zero = {0.0f, 0.0f, 0.0f, 0.0f};
    f32x4 r0,r1,r2,r3,r4,r5,r6,r7;
#pragma unroll
    for (int e = 0; e < 4; ++e) {
        r0[e]=3.0e38f; r1[e]=3.0e38f; r2[e]=3.0e38f; r3[e]=3.0e38f;
        r4[e]=3.0e38f; r5[e]=3.0e38f; r6[e]=3.0e38f; r7[e]=3.0e38f;
    }

    // All 64 lanes load the same 32 fragment slots (lane&31): halves distinct
    // bytes; lanes 32-63 get duplicate finite data (zeroed by A's k-groups).
    const uint4* __restrict__ bp =
        panel + (size_t)(b * 256 + cg * 64) * 32 + (lane & 31);

#define CD_COMPUTE(C0, C1)                                                   \
    do {                                                                     \
        const short8 bf0 = *reinterpret_cast<const short8*>(&(C0));          \
        const short8 bf1 = *reinterpret_cast<const short8*>(&(C1));          \
        f32x4 d0, d1;                                                        \
        d0 = __builtin_amdgcn_mfma_f32_16x16x32_bf16(a0, bf0, zero, 0,0,0);  \
        d1 = __builtin_amdgcn_mfma_f32_16x16x32_bf16(a0, bf1, zero, 0,0,0);  \
        _Pragma("unroll") for (int e = 0; e < 4; ++e)                        \
            r0[e] = fminf(r0[e], fminf(d0[e], d1[e]));                       \
        d0 = __builtin_amdgcn_mfma_f32_16x16x32_bf16(a1, bf0, zero, 0,0,0);  \
        d1 = __builtin_amdgcn_mfma_f32_16x16x32_bf16(a1, bf1, zero, 0,0,0);  \
        _Pragma("unroll") for (int e = 0; e < 4; ++e)                        \
            r1[e] = fminf(r1[e], fminf(d0[e], d1[e]));                       \
        d0 = __builtin_amdgcn_mfma_f32_16x16x32_bf16(a2, bf0, zero, 0,0,0);  \
        d1 = __builtin_amdgcn_mfma_f32_16x16x32_bf16(a2, bf1, zero, 0,0,0);  \
        _Pragma("unroll") for (int e = 0; e < 4; ++e)                        \
            r2[e] = fminf(r2[e], fminf(d0[e], d1[e]));                       \
        d0 = __builtin_amdgcn_mfma_f32_16x16x32_bf16(a3, bf0, zero, 0,0,0);  \
        d1 = __builtin_amdgcn_mfma_f32_16x16x32_bf16(a3, bf1, zero, 0,0,0);  \
        _Pragma("unroll") for (int e = 0; e < 4; ++e)                        \
            r3[e] = fminf(r3[e], fminf(d0[e], d1[e]));                       \
        d0 = __builtin_amdgcn_mfma_f32_16x16x32_bf16(a4, bf0, zero, 0,0,0);  \
        d1 = __builtin_amdgcn_mfma_f32_16x16x32_bf16(a4, bf1, zero, 0,0,0);  \
        _Pragma("unroll") for (int e = 0; e < 4; ++e)                        \
            r4[e] = fminf(r4[e], fminf(d0[e], d1[e]));                       \
        d0 = __builtin_amdgcn_mfma_f32_16x16x32_bf16(a5, bf0, zero, 0,0,0);  \
        d1 = __builtin_amdgcn_mfma_f32_16x16x32_bf16(a5, bf1, zero, 0,0,0);  \
        _Pragma("unroll") for (int e = 0; e < 4; ++e)                        \
            r5[e] = fminf(r5[e], fminf(d0[e], d1[e]));                       \
        d0 = __builtin_amdgcn_mfma_f32_16x16x32_bf16(a6, bf0, zero, 0,0,0);  \
        d1 = __builtin_amdgcn_mfma_f32_16x16x32_bf16(a6, bf1, zero, 0,0,0);  \
        _Pragma("unroll") for (int e = 0; e < 4; ++e)                        \
            r6[e] = fminf(r6[e], fminf(d0[e], d1[e]));                       \
        d0 = __builtin_amdgcn_mfma_f32_16x16x32_bf16(a7, bf0, zero, 0,0,0);  \
        d1 = __builtin_amdgcn_mfma_f32_16x16x32_bf16(a7, bf1, zero, 0,0,0);  \
        _Pragma("unroll") for (int e = 0; e < 4; ++e)                        \
            r7[e] = fminf(r7[e], fminf(d0[e], d1[e]));                       \
    } while (0)

    // 64 tiles = 32 pairs.  Depth-1 pair pipeline: load pair j+1 before
    // computing pair j (~200 cyc compute covers the L2 hit).  16 VGPR state.
    uint4 c0 = bp[0], c1 = bp[32];
    size_t off = 64;                                  // uint4 units (tile = 32)
#pragma unroll 1
    for (int i = 0; i < 31; ++i) {
        uint4 n0 = bp[off], n1 = bp[off + 32];
        off += 64;
        CD_COMPUTE(c0, c1);
        c0 = n0; c1 = n1;
    }
    CD_COMPUTE(c0, c1);
#undef CD_COMPUTE

    // Row epilogue: butterfly over the 16 cols (within each 16-lane group),
    // then atomicMin per row.  Row = s*16 + (lane>>4)*4 + e  (m89/m91 layout).
    const int rgrp = lane >> 4;
#pragma unroll
    for (int s = 0; s < 8; ++s) {
        f32x4 rv = (s==0)?r0:(s==1)?r1:(s==2)?r2:(s==3)?r3:(s==4)?r4:(s==5)?r5:(s==6)?r6:r7;
#pragma unroll
        for (int e = 0; e < 4; ++e) {
            float v = rv[e];
            v = fminf(v, __shfl_xor(v, 1));
            v = fminf(v, __shfl_xor(v, 2));
            v = fminf(v, __shfl_xor(v, 4));
            v = fminf(v, __shfl_xor(v, 8));
            if ((lane & 15) == 0)
                atomicMin(&outmin[rowbase + s * 16 + rgrp * 4 + e],
                          __float_as_uint(fmaxf(v, 0.0f)));
        }
    }
}

// ---------------- deterministic two-stage sum ----------------
__global__ __launch_bounds__(256) void cd_reduce1(const float* __restrict__ wsmin,
                                                  float* __restrict__ partial) {
    __shared__ float sred[256];
    const float4* __restrict__ v = (const float4*)wsmin;
    const int i = blockIdx.x * 256 + threadIdx.x;     // 128*256 == 2*TOTAL/4
    float4 x = v[i];
    sred[threadIdx.x] = (x.x + x.y) + (x.z + x.w);
    __syncthreads();
    for (int st = 128; st > 0; st >>= 1) {
        if (threadIdx.x < st) sred[threadIdx.x] += sred[threadIdx.x + st];
        __syncthreads();
    }
    if (threadIdx.x == 0) partial[blockIdx.x] = sred[0];
}

__global__ __launch_bounds__(NPART) void cd_reduce2(const float* __restrict__ partial,
                                                    float* __restrict__ out) {
    __shared__ float sred[NPART];
    sred[threadIdx.x] = partial[threadIdx.x];
    __syncthreads();
    for (int st = NPART / 2; st > 0; st >>= 1) {
        if (threadIdx.x < st) sred[threadIdx.x] += sred[threadIdx.x + st];
        __syncthreads();
    }
    if (threadIdx.x == 0) out[0] = sred[0] * (1.0f / (float)BQ);
}

// ---------------- fallback (ws too small): R2 LDS-scalar path ----------------
__global__ __launch_bounds__(256) void cd_init_ws(unsigned int* __restrict__ ws) {
    ws[blockIdx.x * 256 + threadIdx.x] = 0x7F800000u;
}
#define F_APT 8
__global__ __launch_bounds__(256) void cd_min_lds(
        const float* __restrict__ p1, const float* __restrict__ p2,
        unsigned int* __restrict__ wsmin) {
    const int dir = blockIdx.y;
    const float* __restrict__ Aset = dir ? p2 : p1;
    const float* __restrict__ Bset = dir ? p1 : p2;
    unsigned int* __restrict__ outmin = wsmin + dir * TOTAL;
    const int atile = blockIdx.x / 16;
    const int mtile = blockIdx.x % 16;
    const int a0 = atile * 2048;
    const int m0 = (a0 / NPTS) * NPTS + mtile * 256;
    __shared__ float4 sbf[256];
    {
        const float* bpn = Bset + (size_t)(m0 + threadIdx.x) * 3;
        float bx = bpn[0], by = bpn[1], bz = bpn[2];
        sbf[threadIdx.x] = make_float4(-2.0f*bx, -2.0f*by, -2.0f*bz,
                                       fmaf(bx,bx,fmaf(by,by,bz*bz)));
    }
    __syncthreads();
    float ax[F_APT], ay[F_APT], az_[F_APT], q2[F_APT], mn[F_APT];
#pragma unroll
    for (int k = 0; k < F_APT; ++k) {
        const int ai = a0 + k*256 + threadIdx.x;
        const float* ap = Aset + (size_t)ai * 3;
        ax[k]=ap[0]; ay[k]=ap[1]; az_[k]=ap[2];
        q2[k]=fmaf(ax[k],ax[k],fmaf(ay[k],ay[k],az_[k]*az_[k]));
        mn[k]=3.0e38f;
    }
#pragma unroll 2
    for (int j = 0; j < 256; j += 2) {
        const float4 b0 = sbf[j], b1 = sbf[j+1];
#pragma unroll
        for (int k = 0; k < F_APT; ++k) {
            float d0 = fmaf(az_[k],b0.z,b0.w); d0=fmaf(ay[k],b0.y,d0); d0=fmaf(ax[k],b0.x,d0);
            float d1 = fmaf(az_[k],b1.z,b1.w); d1=fmaf(ay[k],b1.y,d1); d1=fmaf(ax[k],b1.x,d1);
            mn[k] = fminf(fminf(mn[k], d0), d1);
        }
    }
#pragma unroll
    for (int k = 0; k < F_APT; ++k) {
        const int ai = a0 + k*256 + threadIdx.x;
        atomicMin(&outmin[ai], __float_as_uint(fmaxf(q2[k]+mn[k], 0.0f)));
    }
}
__global__ __launch_bounds__(1024) void cd_reduce_single(const float* __restrict__ wsmin,
                                                         float* __restrict__ out) {
    __shared__ float sred[1024];
    const float4* __restrict__ v = (const float4*)wsmin;
    float s = 0.0f;
    for (int i = threadIdx.x; i < (2*TOTAL)/4; i += 1024) {
        float4 x = v[i]; s += (x.x + x.y) + (x.z + x.w);
    }
    sred[threadIdx.x] = s;
    __syncthreads();
    for (int st = 512; st > 0; st >>= 1) {
        if (threadIdx.x < st) sred[threadIdx.x] += sred[threadIdx.x + st];
        __syncthreads();
    }
    if (threadIdx.x == 0) out[0] = sred[0] * (1.0f / (float)BQ);
}

extern "C" void kernel_launch(void* const* d_in, const int* in_sizes, int n_in,
                              void* d_out, int out_size, void* d_ws, size_t ws_size,
                              hipStream_t stream) {
    const float* p1 = (const float*)d_in[0];
    const float* p2 = (const float*)d_in[1];
    float* out = (float*)d_out;

    if (ws_size >= WS_NEED) {
        unsigned* wsmin = (unsigned*)d_ws;
        uint4* panels  = (uint4*)((char*)d_ws + WS_MIN_BYTES);
        float* partial = (float*)((char*)d_ws + WS_MIN_BYTES + 2 * PANEL_U4_SIDE * 16);

        cd_prep<<<1024, 256, 0, stream>>>(p1, p2, wsmin, panels);
        dim3 grid(512, 2, 1);
        cd_pass<<<grid, 256, 0, stream>>>(p1, p2, panels, wsmin);
        cd_reduce1<<<128, 256, 0, stream>>>((const float*)wsmin, partial);
        cd_reduce2<<<1, NPART, 0, stream>>>(partial, out);
    } else {
        unsigned* wsmin = (unsigned*)d_ws;                   // 512 KiB
        cd_init_ws<<<(2 * TOTAL) / 256, 256, 0, stream>>>(wsmin);
        dim3 grid(512, 2, 1);
        cd_min_lds<<<grid, 256, 0, stream>>>(p1, p2, wsmin);
        cd_reduce_single<<<1, 1024, 0, stream>>>((const float*)wsmin, out);
    }
}

// Round 12
// 41.958 us; speedup vs baseline: 1.8042x; 1.0340x over previous
//
#include <hip/hip_runtime.h>

// ChamferDistance  B=16, N=M=4096, D=3, fp32 in/out (scalar out).
// Two MFMA passes fused into one kernel launch (grid.y = dir).
// d(a,b) = sum_k A[k]*B[k], 13 bf16 hi/lo slots in K=32 (k-groups 0,1 real;
// k-groups 2,3 zero in A).  Panel built in LDS per block; no atomics.
#define BQ     16
#define NPTS   4096
#define TOTAL  (BQ * NPTS)              // 65536 points per side
#define NPART  128

// ws layout: rowmin[8][TOTAL] floats (2 dirs x 4 colgroups), then partials.
#define ROWMIN_FLOATS ((size_t)8 * TOTAL)
#define WS_NEED (ROWMIN_FLOATS * 4 + (size_t)NPART * 4)

typedef __attribute__((ext_vector_type(8))) short short8;
typedef __attribute__((ext_vector_type(4))) float f32x4;

__device__ __forceinline__ unsigned short f2bf(float x) {
    union { float f; unsigned u; } v; v.f = x;
    unsigned r = v.u + 0x7FFFu + ((v.u >> 16) & 1u);    // RNE
    return (unsigned short)(r >> 16);
}
__device__ __forceinline__ float bf2f(unsigned short h) {
    union { float f; unsigned u; } v; v.u = ((unsigned)h) << 16; return v.f;
}
#define BF_ONE 0x3F80

// B-role, k-position (g, j), g = lane32>>4:
//  g0: m2xh m2yh m2zh m2xl m2yl m2zl m2xh m2yh
//  g1: m2zh  1    1   b2H  b2L   0    0    0
__device__ __forceinline__ uint4 make_bslots16(const float* __restrict__ pts,
                                               int tile, int lane32) {
    const int g = lane32 >> 4;
    const float* pp = pts + (size_t)(tile * 16 + (lane32 & 15)) * 3;
    const float x = pp[0], y = pp[1], z = pp[2];
    const unsigned short xh = f2bf(x), yh = f2bf(y), zh = f2bf(z);
    const unsigned short xl = f2bf(x - bf2f(xh)), yl = f2bf(y - bf2f(yh)),
                         zl = f2bf(z - bf2f(zh));
    const unsigned short m2xh = f2bf(-2.0f * bf2f(xh)), m2yh = f2bf(-2.0f * bf2f(yh)),
                         m2zh = f2bf(-2.0f * bf2f(zh));
    const unsigned short m2xl = f2bf(-2.0f * bf2f(xl)), m2yl = f2bf(-2.0f * bf2f(yl)),
                         m2zl = f2bf(-2.0f * bf2f(zl));
    const float s2 = fmaf(x, x, fmaf(y, y, z * z));
    const unsigned short s2h = f2bf(s2);
    const unsigned short s2l = f2bf(s2 - bf2f(s2h));
    unsigned short s[8];
    if (g == 0) { s[0]=m2xh; s[1]=m2yh; s[2]=m2zh; s[3]=m2xl;   s[4]=m2yl;   s[5]=m2zl; s[6]=m2xh; s[7]=m2yh; }
    else        { s[0]=m2zh; s[1]=BF_ONE; s[2]=BF_ONE; s[3]=s2h; s[4]=s2l;   s[5]=0;    s[6]=0;    s[7]=0;    }
    uint4 o;
    o.x = (unsigned)s[0] | ((unsigned)s[1] << 16);
    o.y = (unsigned)s[2] | ((unsigned)s[3] << 16);
    o.z = (unsigned)s[4] | ((unsigned)s[5] << 16);
    o.w = (unsigned)s[6] | ((unsigned)s[7] << 16);
    return o;
}

// A-role paired with B above:
//  g0: xh yh zh xh yh zh xl yl
//  g1: zl s2h s2l 1 1 0 0 0
__device__ __forceinline__ short8 make_aslots16(const float* __restrict__ pts,
                                                int point, int g) {
    const float* pp = pts + (size_t)point * 3;
    const float x = pp[0], y = pp[1], z = pp[2];
    const unsigned short xh = f2bf(x), yh = f2bf(y), zh = f2bf(z);
    const unsigned short xl = f2bf(x - bf2f(xh)), yl = f2bf(y - bf2f(yh)),
                         zl = f2bf(z - bf2f(zh));
    const float s2 = fmaf(x, x, fmaf(y, y, z * z));
    const unsigned short s2h = f2bf(s2);
    const unsigned short s2l = f2bf(s2 - bf2f(s2h));
    unsigned short s[8];
    if (g == 0) { s[0]=xh; s[1]=yh; s[2]=zh; s[3]=xh;     s[4]=yh;     s[5]=zh; s[6]=xl; s[7]=yl; }
    else        { s[0]=zl; s[1]=s2h; s[2]=s2l; s[3]=BF_ONE; s[4]=BF_ONE; s[5]=0; s[6]=0; s[7]=0; }
    union { unsigned u[4]; short8 v; } o;
    o.u[0] = (unsigned)s[0] | ((unsigned)s[1] << 16);
    o.u[1] = (unsigned)s[2] | ((unsigned)s[3] << 16);
    o.u[2] = (unsigned)s[4] | ((unsigned)s[5] << 16);
    o.u[3] = (unsigned)s[6] | ((unsigned)s[7] << 16);
    return o.v;
}

// Main fused kernel.  Block = 4 waves (512 rows); wave = 128 rows (8 subtiles).
// Block builds its colgroup's 64-tile B panel in LDS (32 KB), one barrier,
// then each wave sweeps the 64 tiles starting at wave*16 (desync).
// Row-mins written to private (dir,cg) slice -> no atomics, no init kernel.
// grid = (16 batches * 8 rowgroups * 4 colgroups, 2 dirs) = (512, 2).
__global__ __launch_bounds__(256, 4) void cd_main(
        const float* __restrict__ p1, const float* __restrict__ p2,
        float* __restrict__ rowmin) {
    const int dir  = blockIdx.y;
    const float* __restrict__ A  = dir ? p2 : p1;
    const float* __restrict__ Bp = dir ? p1 : p2;

    const int bx   = blockIdx.x;
    const int b    = bx >> 5;                         // batch
    const int rg   = (bx >> 2) & 7;                   // rowgroup (512 rows)
    const int cg   = bx & 3;                          // colgroup (64 col-tiles)
    const int wave = threadIdx.x >> 6;
    const int lane = threadIdx.x & 63;
    const int half = lane >> 5;                       // 0: real k-groups, 1: zero-A

    __shared__ uint4 spanel[64 * 32];                 // 32 KB: 64 tiles x 32 slots

    // Build panel from raw points (1024 col-points of this colgroup).
    const float* __restrict__ Bbase = Bp + (size_t)(b * NPTS + cg * 1024) * 3;
#pragma unroll
    for (int k = 0; k < 8; ++k) {
        const int s = threadIdx.x + k * 256;          // 2048 slots
        spanel[s] = make_bslots16(Bbase, s >> 5, s & 31);
    }

    const int rowbase = b * NPTS + rg * 512 + wave * 128;

    // A fragments: 8 subtiles of 16 rows; lanes >=32 carry zero k-groups.
    short8 az; { union { unsigned u[4]; short8 v; } z = {{0,0,0,0}}; az = z.v; }
    short8 a0=az,a1=az,a2=az,a3=az,a4=az,a5=az,a6=az,a7=az;
    if (half == 0) {
        const int g = (lane >> 4) & 1, r = lane & 15;
        a0 = make_aslots16(A, rowbase +   0 + r, g);
        a1 = make_aslots16(A, rowbase +  16 + r, g);
        a2 = make_aslots16(A, rowbase +  32 + r, g);
        a3 = make_aslots16(A, rowbase +  48 + r, g);
        a4 = make_aslots16(A, rowbase +  64 + r, g);
        a5 = make_aslots16(A, rowbase +  80 + r, g);
        a6 = make_aslots16(A, rowbase +  96 + r, g);
        a7 = make_aslots16(A, rowbase + 112 + r, g);
    }

    f32x4 zero = {0.0f, 0.0f, 0.0f, 0.0f};
    f32x4 r0,r1,r2,r3,r4,r5,r6,r7;
#pragma unroll
    for (int e = 0; e < 4; ++e) {
        r0[e]=3.0e38f; r1[e]=3.0e38f; r2[e]=3.0e38f; r3[e]=3.0e38f;
        r4[e]=3.0e38f; r5[e]=3.0e38f; r6[e]=3.0e38f; r7[e]=3.0e38f;
    }

    __syncthreads();                                  // panel ready (read-only after)

#define CD_COMPUTE(C0, C1)                                                   \
    do {                                                                     \
        const short8 bf0 = *reinterpret_cast<const short8*>(&(C0));          \
        const short8 bf1 = *reinterpret_cast<const short8*>(&(C1));          \
        f32x4 d0, d1;                                                        \
        d0 = __builtin_amdgcn_mfma_f32_16x16x32_bf16(a0, bf0, zero, 0,0,0);  \
        d1 = __builtin_amdgcn_mfma_f32_16x16x32_bf16(a0, bf1, zero, 0,0,0);  \
        _Pragma("unroll") for (int e = 0; e < 4; ++e)                        \
            r0[e] = fminf(r0[e], fminf(d0[e], d1[e]));                       \
        d0 = __builtin_amdgcn_mfma_f32_16x16x32_bf16(a1, bf0, zero, 0,0,0);  \
        d1 = __builtin_amdgcn_mfma_f32_16x16x32_bf16(a1, bf1, zero, 0,0,0);  \
        _Pragma("unroll") for (int e = 0; e < 4; ++e)                        \
            r1[e] = fminf(r1[e], fminf(d0[e], d1[e]));                       \
        d0 = __builtin_amdgcn_mfma_f32_16x16x32_bf16(a2, bf0, zero, 0,0,0);  \
        d1 = __builtin_amdgcn_mfma_f32_16x16x32_bf16(a2, bf1, zero, 0,0,0);  \
        _Pragma("unroll") for (int e = 0; e < 4; ++e)                        \
            r2[e] = fminf(r2[e], fminf(d0[e], d1[e]));                       \
        d0 = __builtin_amdgcn_mfma_f32_16x16x32_bf16(a3, bf0, zero, 0,0,0);  \
        d1 = __builtin_amdgcn_mfma_f32_16x16x32_bf16(a3, bf1, zero, 0,0,0);  \
        _Pragma("unroll") for (int e = 0; e < 4; ++e)                        \
            r3[e] = fminf(r3[e], fminf(d0[e], d1[e]));                       \
        d0 = __builtin_amdgcn_mfma_f32_16x16x32_bf16(a4, bf0, zero, 0,0,0);  \
        d1 = __builtin_amdgcn_mfma_f32_16x16x32_bf16(a4, bf1, zero, 0,0,0);  \
        _Pragma("unroll") for (int e = 0; e < 4; ++e)                        \
            r4[e] = fminf(r4[e], fminf(d0[e], d1[e]));                       \
        d0 = __builtin_amdgcn_mfma_f32_16x16x32_bf16(a5, bf0, zero, 0,0,0);  \
        d1 = __builtin_amdgcn_mfma_f32_16x16x32_bf16(a5, bf1, zero, 0,0,0);  \
        _Pragma("unroll") for (int e = 0; e < 4; ++e)                        \
            r5[e] = fminf(r5[e], fminf(d0[e], d1[e]));                       \
        d0 = __builtin_amdgcn_mfma_f32_16x16x32_bf16(a6, bf0, zero, 0,0,0);  \
        d1 = __builtin_amdgcn_mfma_f32_16x16x32_bf16(a6, bf1, zero, 0,0,0);  \
        _Pragma("unroll") for (int e = 0; e < 4; ++e)                        \
            r6[e] = fminf(r6[e], fminf(d0[e], d1[e]));                       \
        d0 = __builtin_amdgcn_mfma_f32_16x16x32_bf16(a7, bf0, zero, 0,0,0);  \
        d1 = __builtin_amdgcn_mfma_f32_16x16x32_bf16(a7, bf1, zero, 0,0,0);  \
        _Pragma("unroll") for (int e = 0; e < 4; ++e)                        \
            r7[e] = fminf(r7[e], fminf(d0[e], d1[e]));                       \
    } while (0)

    // 64 tiles = 32 pairs from LDS; wave starts at wave*16 (desync waves).
    // Depth-1 register prefetch covers ds_read latency (~120cyc < compute).
    const int sl = lane & 31;
    int idx = wave * 16;
    uint4 c0 = spanel[idx * 32 + sl], c1 = spanel[(idx + 1) * 32 + sl];
#pragma unroll 1
    for (int i = 0; i < 31; ++i) {
        const int nidx = (idx + 2) & 63;
        uint4 n0 = spanel[nidx * 32 + sl];
        uint4 n1 = spanel[(nidx + 1) * 32 + sl];
        CD_COMPUTE(c0, c1);
        c0 = n0; c1 = n1; idx = nidx;
    }
    CD_COMPUTE(c0, c1);
#undef CD_COMPUTE

    // Row epilogue: butterfly over the 16 cols (within each 16-lane group),
    // direct store (no atomics).  Row = s*16 + (lane>>4)*4 + e (m89/m91).
    float* __restrict__ outr = rowmin + (size_t)(dir * 4 + cg) * TOTAL;
    const int rgrp = lane >> 4;
#pragma unroll
    for (int s = 0; s < 8; ++s) {
        f32x4 rv = (s==0)?r0:(s==1)?r1:(s==2)?r2:(s==3)?r3:(s==4)?r4:(s==5)?r5:(s==6)?r6:r7;
#pragma unroll
        for (int e = 0; e < 4; ++e) {
            float v = rv[e];
            v = fminf(v, __shfl_xor(v, 1));
            v = fminf(v, __shfl_xor(v, 2));
            v = fminf(v, __shfl_xor(v, 4));
            v = fminf(v, __shfl_xor(v, 8));
            if ((lane & 15) == 0)
                outr[rowbase + s * 16 + rgrp * 4 + e] = fmaxf(v, 0.0f);
        }
    }
}

// Combine 4 colgroup slices per (dir,row), sum -> 128 block partials.
__global__ __launch_bounds__(256) void cd_combine(const float* __restrict__ rowmin,
                                                  float* __restrict__ partial) {
    __shared__ float sred[256];
    const int tid = blockIdx.x * 256 + threadIdx.x;   // [0, 32768)
    float s = 0.0f;
#pragma unroll
    for (int k = 0; k < 4; ++k) {
        const int i   = tid + k * 32768;              // [0, 131072)
        const int d   = i >> 16;                      // dir
        const int row = i & (TOTAL - 1);
        const float* base = rowmin + (size_t)d * 4 * TOTAL + row;
        s += fminf(fminf(base[0], base[TOTAL]),
                   fminf(base[2 * TOTAL], base[3 * TOTAL]));
    }
    sred[threadIdx.x] = s;
    __syncthreads();
    for (int st = 128; st > 0; st >>= 1) {
        if (threadIdx.x < st) sred[threadIdx.x] += sred[threadIdx.x + st];
        __syncthreads();
    }
    if (threadIdx.x == 0) partial[blockIdx.x] = sred[0];
}

__global__ __launch_bounds__(NPART) void cd_final(const float* __restrict__ partial,
                                                  float* __restrict__ out) {
    __shared__ float sred[NPART];
    sred[threadIdx.x] = partial[threadIdx.x];
    __syncthreads();
    for (int st = NPART / 2; st > 0; st >>= 1) {
        if (threadIdx.x < st) sred[threadIdx.x] += sred[threadIdx.x + st];
        __syncthreads();
    }
    if (threadIdx.x == 0) out[0] = sred[0] * (1.0f / (float)BQ);
}

// ---------------- fallback (ws too small): R2 LDS-scalar path ----------------
__global__ __launch_bounds__(256) void cd_init_ws(unsigned int* __restrict__ ws) {
    ws[blockIdx.x * 256 + threadIdx.x] = 0x7F800000u;
}
#define F_APT 8
__global__ __launch_bounds__(256) void cd_min_lds(
        const float* __restrict__ p1, const float* __restrict__ p2,
        unsigned int* __restrict__ wsmin) {
    const int dir = blockIdx.y;
    const float* __restrict__ Aset = dir ? p2 : p1;
    const float* __restrict__ Bset = dir ? p1 : p2;
    unsigned int* __restrict__ outmin = wsmin + dir * TOTAL;
    const int atile = blockIdx.x / 16;
    const int mtile = blockIdx.x % 16;
    const int a0 = atile * 2048;
    const int m0 = (a0 / NPTS) * NPTS + mtile * 256;
    __shared__ float4 sbf[256];
    {
        const float* bpn = Bset + (size_t)(m0 + threadIdx.x) * 3;
        float bx = bpn[0], by = bpn[1], bz = bpn[2];
        sbf[threadIdx.x] = make_float4(-2.0f*bx, -2.0f*by, -2.0f*bz,
                                       fmaf(bx,bx,fmaf(by,by,bz*bz)));
    }
    __syncthreads();
    float ax[F_APT], ay[F_APT], az_[F_APT], q2[F_APT], mn[F_APT];
#pragma unroll
    for (int k = 0; k < F_APT; ++k) {
        const int ai = a0 + k*256 + threadIdx.x;
        const float* ap = Aset + (size_t)ai * 3;
        ax[k]=ap[0]; ay[k]=ap[1]; az_[k]=ap[2];
        q2[k]=fmaf(ax[k],ax[k],fmaf(ay[k],ay[k],az_[k]*az_[k]));
        mn[k]=3.0e38f;
    }
#pragma unroll 2
    for (int j = 0; j < 256; j += 2) {
        const float4 b0 = sbf[j], b1 = sbf[j+1];
#pragma unroll
        for (int k = 0; k < F_APT; ++k) {
            float d0 = fmaf(az_[k],b0.z,b0.w); d0=fmaf(ay[k],b0.y,d0); d0=fmaf(ax[k],b0.x,d0);
            float d1 = fmaf(az_[k],b1.z,b1.w); d1=fmaf(ay[k],b1.y,d1); d1=fmaf(ax[k],b1.x,d1);
            mn[k] = fminf(fminf(mn[k], d0), d1);
        }
    }
#pragma unroll
    for (int k = 0; k < F_APT; ++k) {
        const int ai = a0 + k*256 + threadIdx.x;
        atomicMin(&outmin[ai], __float_as_uint(fmaxf(q2[k]+mn[k], 0.0f)));
    }
}
__global__ __launch_bounds__(1024) void cd_reduce_single(const float* __restrict__ wsmin,
                                                         float* __restrict__ out) {
    __shared__ float sred[1024];
    const float4* __restrict__ v = (const float4*)wsmin;
    float s = 0.0f;
    for (int i = threadIdx.x; i < (2*TOTAL)/4; i += 1024) {
        float4 x = v[i]; s += (x.x + x.y) + (x.z + x.w);
    }
    sred[threadIdx.x] = s;
    __syncthreads();
    for (int st = 512; st > 0; st >>= 1) {
        if (threadIdx.x < st) sred[threadIdx.x] += sred[threadIdx.x + st];
        __syncthreads();
    }
    if (threadIdx.x == 0) out[0] = sred[0] * (1.0f / (float)BQ);
}

extern "C" void kernel_launch(void* const* d_in, const int* in_sizes, int n_in,
                              void* d_out, int out_size, void* d_ws, size_t ws_size,
                              hipStream_t stream) {
    const float* p1 = (const float*)d_in[0];
    const float* p2 = (const float*)d_in[1];
    float* out = (float*)d_out;

    if (ws_size >= WS_NEED) {
        float* rowmin  = (float*)d_ws;                      // 2 MiB
        float* partial = (float*)((char*)d_ws + ROWMIN_FLOATS * 4);

        dim3 grid(512, 2, 1);
        cd_main<<<grid, 256, 0, stream>>>(p1, p2, rowmin);
        cd_combine<<<128, 256, 0, stream>>>(rowmin, partial);
        cd_final<<<1, NPART, 0, stream>>>(partial, out);
    } else {
        unsigned* wsmin = (unsigned*)d_ws;                  // 512 KiB
        cd_init_ws<<<(2 * TOTAL) / 256, 256, 0, stream>>>(wsmin);
        dim3 grid(512, 2, 1);
        cd_min_lds<<<grid, 256, 0, stream>>>(p1, p2, wsmin);
        cd_reduce_single<<<1, 1024, 0, stream>>>((const float*)wsmin, out);
    }
}

// Round 13
// 40.583 us; speedup vs baseline: 1.8654x; 1.0339x over previous
//
#include <hip/hip_runtime.h>

// ChamferDistance  B=16, N=M=4096, D=3, fp32 in/out (scalar out).
// Fused MFMA kernel (grid.y = dir), 32x32x16 bf16 MFMA: K=16 exactly fits the
// 13 hi/lo slots (no zero-padding waste; 16x16x32 wasted half its K).
// Panel in LDS per block; private rowmin slices; no atomics.
#define BQ     16
#define NPTS   4096
#define TOTAL  (BQ * NPTS)              // 65536 points per side
#define NPART  128

// ws layout: rowmin[8][TOTAL] floats (2 dirs x 4 colgroups), then partials.
#define ROWMIN_FLOATS ((size_t)8 * TOTAL)
#define WS_NEED (ROWMIN_FLOATS * 4 + (size_t)NPART * 4)

typedef __attribute__((ext_vector_type(8)))  short short8;
typedef __attribute__((ext_vector_type(16))) float f32x16;

__device__ __forceinline__ unsigned short f2bf(float x) {
    union { float f; unsigned u; } v; v.f = x;
    unsigned r = v.u + 0x7FFFu + ((v.u >> 16) & 1u);    // RNE
    return (unsigned short)(r >> 16);
}
__device__ __forceinline__ float bf2f(unsigned short h) {
    union { float f; unsigned u; } v; v.u = ((unsigned)h) << 16; return v.f;
}
#define BF_ONE 0x3F80

// ---- R5/R7-verified 32x32x16 slot maps (absmax=0) ----
// B-role slots, k = 8*g + j, g = lane>>5:
//  g0: m2xh m2yh m2zh m2xl m2yl m2zl m2xh m2yh
//  g1: m2zh  1    1   b2H  b2L   0    0    0
__device__ __forceinline__ uint4 make_bslots(const float* __restrict__ pts,
                                             int tile, int lane) {
    const int pidx = lane & 31, g = lane >> 5;
    const float* pp = pts + (size_t)(tile * 32 + pidx) * 3;
    const float x = pp[0], y = pp[1], z = pp[2];
    const unsigned short xh = f2bf(x), yh = f2bf(y), zh = f2bf(z);
    const unsigned short xl = f2bf(x - bf2f(xh)), yl = f2bf(y - bf2f(yh)),
                         zl = f2bf(z - bf2f(zh));
    const unsigned short m2xh = f2bf(-2.0f * bf2f(xh)), m2yh = f2bf(-2.0f * bf2f(yh)),
                         m2zh = f2bf(-2.0f * bf2f(zh));
    const unsigned short m2xl = f2bf(-2.0f * bf2f(xl)), m2yl = f2bf(-2.0f * bf2f(yl)),
                         m2zl = f2bf(-2.0f * bf2f(zl));
    const float s2 = fmaf(x, x, fmaf(y, y, z * z));
    const unsigned short s2h = f2bf(s2);
    const unsigned short s2l = f2bf(s2 - bf2f(s2h));
    unsigned short s[8];
    if (g == 0) { s[0]=m2xh; s[1]=m2yh; s[2]=m2zh; s[3]=m2xl; s[4]=m2yl; s[5]=m2zl; s[6]=m2xh; s[7]=m2yh; }
    else        { s[0]=m2zh; s[1]=BF_ONE; s[2]=BF_ONE; s[3]=s2h; s[4]=s2l; s[5]=0; s[6]=0; s[7]=0; }
    uint4 o;
    o.x = (unsigned)s[0] | ((unsigned)s[1] << 16);
    o.y = (unsigned)s[2] | ((unsigned)s[3] << 16);
    o.z = (unsigned)s[4] | ((unsigned)s[5] << 16);
    o.w = (unsigned)s[6] | ((unsigned)s[7] << 16);
    return o;
}

// A-role slots paired with B: g0: xh yh zh xh yh zh xl yl ; g1: zl s2h s2l 1 1 0 0 0
__device__ __forceinline__ short8 make_aslots(const float* __restrict__ pts,
                                              int point, int g) {
    const float* pp = pts + (size_t)point * 3;
    const float x = pp[0], y = pp[1], z = pp[2];
    const unsigned short xh = f2bf(x), yh = f2bf(y), zh = f2bf(z);
    const unsigned short xl = f2bf(x - bf2f(xh)), yl = f2bf(y - bf2f(yh)),
                         zl = f2bf(z - bf2f(zh));
    const float s2 = fmaf(x, x, fmaf(y, y, z * z));
    const unsigned short s2h = f2bf(s2);
    const unsigned short s2l = f2bf(s2 - bf2f(s2h));
    unsigned short s[8];
    if (g == 0) { s[0]=xh; s[1]=yh; s[2]=zh; s[3]=xh; s[4]=yh; s[5]=zh; s[6]=xl; s[7]=yl; }
    else        { s[0]=zl; s[1]=s2h; s[2]=s2l; s[3]=BF_ONE; s[4]=BF_ONE; s[5]=0; s[6]=0; s[7]=0; }
    union { unsigned u[4]; short8 v; } o;
    o.u[0] = (unsigned)s[0] | ((unsigned)s[1] << 16);
    o.u[1] = (unsigned)s[2] | ((unsigned)s[3] << 16);
    o.u[2] = (unsigned)s[4] | ((unsigned)s[5] << 16);
    o.u[3] = (unsigned)s[6] | ((unsigned)s[7] << 16);
    return o.v;
}

// Main kernel.  Block = 4 waves (256 rows); wave = 64 rows (2 x 32-row A-frags).
// Block builds its colgroup's 32-tile (1024-col) B panel in LDS (32 KB), then
// each wave sweeps the 32 tiles (start offset wave*8 desyncs waves).
// grid = (16 batches * 16 rowgroups * 4 colgroups, 2 dirs) = (1024, 2).
__global__ __launch_bounds__(256, 4) void cd_main(
        const float* __restrict__ p1, const float* __restrict__ p2,
        float* __restrict__ rowmin) {
    const int dir  = blockIdx.y;
    const float* __restrict__ A  = dir ? p2 : p1;
    const float* __restrict__ Bp = dir ? p1 : p2;

    const int bx   = blockIdx.x;
    const int b    = bx >> 6;                         // batch
    const int rg   = (bx >> 2) & 15;                  // rowgroup (256 rows)
    const int cg   = bx & 3;                          // colgroup (32 tiles = 1024 cols)
    const int wave = threadIdx.x >> 6;
    const int lane = threadIdx.x & 63;
    const int pidx = lane & 31, g = lane >> 5;

    __shared__ uint4 spanel[32 * 64];                 // 32 KB: 32 tiles x 64 slots

    // Build panel from raw points (1024 col-points of this colgroup).
    const float* __restrict__ Bbase = Bp + (size_t)(b * NPTS + cg * 1024) * 3;
#pragma unroll
    for (int k = 0; k < 8; ++k) {
        const int s = threadIdx.x + k * 256;          // 2048 slots
        spanel[s] = make_bslots(Bbase, s >> 6, s & 63);
    }

    const int rowbase = b * NPTS + rg * 256 + wave * 64;

    const short8 a0 = make_aslots(A, rowbase      + pidx, g);
    const short8 a1 = make_aslots(A, rowbase + 32 + pidx, g);

    f32x16 zero, r0, r1;
#pragma unroll
    for (int e = 0; e < 16; ++e) { zero[e] = 0.0f; r0[e] = 3.0e38f; r1[e] = 3.0e38f; }

    __syncthreads();                                  // panel ready (read-only after)

#define CD_COMPUTE(C0, C1)                                                    \
    do {                                                                      \
        const short8 bf0 = *reinterpret_cast<const short8*>(&(C0));           \
        const short8 bf1 = *reinterpret_cast<const short8*>(&(C1));           \
        f32x16 d0, d1;                                                        \
        d0 = __builtin_amdgcn_mfma_f32_32x32x16_bf16(a0, bf0, zero, 0, 0, 0); \
        d1 = __builtin_amdgcn_mfma_f32_32x32x16_bf16(a0, bf1, zero, 0, 0, 0); \
        _Pragma("unroll") for (int e = 0; e < 16; ++e)                        \
            r0[e] = fminf(r0[e], fminf(d0[e], d1[e]));                        \
        d0 = __builtin_amdgcn_mfma_f32_32x32x16_bf16(a1, bf0, zero, 0, 0, 0); \
        d1 = __builtin_amdgcn_mfma_f32_32x32x16_bf16(a1, bf1, zero, 0, 0, 0); \
        _Pragma("unroll") for (int e = 0; e < 16; ++e)                        \
            r1[e] = fminf(r1[e], fminf(d0[e], d1[e]));                        \
    } while (0)

    // 32 tiles = 16 pairs from LDS; wave starts at tile wave*8 (desync).
    // Depth-1 register prefetch covers ds_read latency.
    int t0 = wave * 8;
    uint4 c0 = spanel[t0 * 64 + lane], c1 = spanel[(t0 + 1) * 64 + lane];
#pragma unroll 1
    for (int i = 0; i < 15; ++i) {
        const int tn = (t0 + 2) & 31;
        uint4 n0 = spanel[tn * 64 + lane];
        uint4 n1 = spanel[(tn + 1) * 64 + lane];
        CD_COMPUTE(c0, c1);
        c0 = n0; c1 = n1; t0 = tn;
    }
    CD_COMPUTE(c0, c1);
#undef CD_COMPUTE

    // Row epilogue: butterfly min over 32 cols (within each 32-lane half),
    // direct store.  Row-in-tile = (e&3) + 8*(e>>2) + 4*g  (m74/m101 layout).
    float* __restrict__ outr = rowmin + (size_t)(dir * 4 + cg) * TOTAL;
#pragma unroll
    for (int e = 0; e < 16; ++e) {
        float v0 = r0[e], v1 = r1[e];
#pragma unroll
        for (int m = 1; m <= 16; m <<= 1) {
            v0 = fminf(v0, __shfl_xor(v0, m));
            v1 = fminf(v1, __shfl_xor(v1, m));
        }
        const int rl = (e & 3) + 8 * (e >> 2) + 4 * g;
        if (pidx == 0) {
            outr[rowbase +      rl] = fmaxf(v0, 0.0f);
            outr[rowbase + 32 + rl] = fmaxf(v1, 0.0f);
        }
    }
}

// Combine 4 colgroup slices per (dir,row), sum -> 128 block partials.
__global__ __launch_bounds__(256) void cd_combine(const float* __restrict__ rowmin,
                                                  float* __restrict__ partial) {
    __shared__ float sred[256];
    const int tid = blockIdx.x * 256 + threadIdx.x;   // [0, 32768)
    float s = 0.0f;
#pragma unroll
    for (int k = 0; k < 4; ++k) {
        const int i   = tid + k * 32768;              // [0, 131072)
        const int d   = i >> 16;                      // dir
        const int row = i & (TOTAL - 1);
        const float* base = rowmin + (size_t)d * 4 * TOTAL + row;
        s += fminf(fminf(base[0], base[TOTAL]),
                   fminf(base[2 * TOTAL], base[3 * TOTAL]));
    }
    sred[threadIdx.x] = s;
    __syncthreads();
    for (int st = 128; st > 0; st >>= 1) {
        if (threadIdx.x < st) sred[threadIdx.x] += sred[threadIdx.x + st];
        __syncthreads();
    }
    if (threadIdx.x == 0) partial[blockIdx.x] = sred[0];
}

__global__ __launch_bounds__(NPART) void cd_final(const float* __restrict__ partial,
                                                  float* __restrict__ out) {
    __shared__ float sred[NPART];
    sred[threadIdx.x] = partial[threadIdx.x];
    __syncthreads();
    for (int st = NPART / 2; st > 0; st >>= 1) {
        if (threadIdx.x < st) sred[threadIdx.x] += sred[threadIdx.x + st];
        __syncthreads();
    }
    if (threadIdx.x == 0) out[0] = sred[0] * (1.0f / (float)BQ);
}

// ---------------- fallback (ws too small): R2 LDS-scalar path ----------------
__global__ __launch_bounds__(256) void cd_init_ws(unsigned int* __restrict__ ws) {
    ws[blockIdx.x * 256 + threadIdx.x] = 0x7F800000u;
}
#define F_APT 8
__global__ __launch_bounds__(256) void cd_min_lds(
        const float* __restrict__ p1, const float* __restrict__ p2,
        unsigned int* __restrict__ wsmin) {
    const int dir = blockIdx.y;
    const float* __restrict__ Aset = dir ? p2 : p1;
    const float* __restrict__ Bset = dir ? p1 : p2;
    unsigned int* __restrict__ outmin = wsmin + dir * TOTAL;
    const int atile = blockIdx.x / 16;
    const int mtile = blockIdx.x % 16;
    const int a0 = atile * 2048;
    const int m0 = (a0 / NPTS) * NPTS + mtile * 256;
    __shared__ float4 sbf[256];
    {
        const float* bpn = Bset + (size_t)(m0 + threadIdx.x) * 3;
        float bx = bpn[0], by = bpn[1], bz = bpn[2];
        sbf[threadIdx.x] = make_float4(-2.0f*bx, -2.0f*by, -2.0f*bz,
                                       fmaf(bx,bx,fmaf(by,by,bz*bz)));
    }
    __syncthreads();
    float ax[F_APT], ay[F_APT], az_[F_APT], q2[F_APT], mn[F_APT];
#pragma unroll
    for (int k = 0; k < F_APT; ++k) {
        const int ai = a0 + k*256 + threadIdx.x;
        const float* ap = Aset + (size_t)ai * 3;
        ax[k]=ap[0]; ay[k]=ap[1]; az_[k]=ap[2];
        q2[k]=fmaf(ax[k],ax[k],fmaf(ay[k],ay[k],az_[k]*az_[k]));
        mn[k]=3.0e38f;
    }
#pragma unroll 2
    for (int j = 0; j < 256; j += 2) {
        const float4 b0 = sbf[j], b1 = sbf[j+1];
#pragma unroll
        for (int k = 0; k < F_APT; ++k) {
            float d0 = fmaf(az_[k],b0.z,b0.w); d0=fmaf(ay[k],b0.y,d0); d0=fmaf(ax[k],b0.x,d0);
            float d1 = fmaf(az_[k],b1.z,b1.w); d1=fmaf(ay[k],b1.y,d1); d1=fmaf(ax[k],b1.x,d1);
            mn[k] = fminf(fminf(mn[k], d0), d1);
        }
    }
#pragma unroll
    for (int k = 0; k < F_APT; ++k) {
        const int ai = a0 + k*256 + threadIdx.x;
        atomicMin(&outmin[ai], __float_as_uint(fmaxf(q2[k]+mn[k], 0.0f)));
    }
}
__global__ __launch_bounds__(1024) void cd_reduce_single(const float* __restrict__ wsmin,
                                                         float* __restrict__ out) {
    __shared__ float sred[1024];
    const float4* __restrict__ v = (const float4*)wsmin;
    float s = 0.0f;
    for (int i = threadIdx.x; i < (2*TOTAL)/4; i += 1024) {
        float4 x = v[i]; s += (x.x + x.y) + (x.z + x.w);
    }
    sred[threadIdx.x] = s;
    __syncthreads();
    for (int st = 512; st > 0; st >>= 1) {
        if (threadIdx.x < st) sred[threadIdx.x] += sred[threadIdx.x + st];
        __syncthreads();
    }
    if (threadIdx.x == 0) out[0] = sred[0] * (1.0f / (float)BQ);
}

extern "C" void kernel_launch(void* const* d_in, const int* in_sizes, int n_in,
                              void* d_out, int out_size, void* d_ws, size_t ws_size,
                              hipStream_t stream) {
    const float* p1 = (const float*)d_in[0];
    const float* p2 = (const float*)d_in[1];
    float* out = (float*)d_out;

    if (ws_size >= WS_NEED) {
        float* rowmin  = (float*)d_ws;                      // 2 MiB
        float* partial = (float*)((char*)d_ws + ROWMIN_FLOATS * 4);

        dim3 grid(1024, 2, 1);
        cd_main<<<grid, 256, 0, stream>>>(p1, p2, rowmin);
        cd_combine<<<128, 256, 0, stream>>>(rowmin, partial);
        cd_final<<<1, NPART, 0, stream>>>(partial, out);
    } else {
        unsigned* wsmin = (unsigned*)d_ws;                  // 512 KiB
        cd_init_ws<<<(2 * TOTAL) / 256, 256, 0, stream>>>(wsmin);
        dim3 grid(512, 2, 1);
        cd_min_lds<<<grid, 256, 0, stream>>>(p1, p2, wsmin);
        cd_reduce_single<<<1, 1024, 0, stream>>>((const float*)wsmin, out);
    }
}